// Round 3
// baseline (629.193 us; speedup 1.0000x reference)
//
#include <hip/hip_runtime.h>
#include <cstdint>
#include <cstddef>

// Problem constants (fixed by reference)
#define BATCH 32
#define SEQ   2048
#define DIM   1024      // ENC_D = DEC_D = ATTN_D = OUT_D = 1024
#define MROWS (BATCH*SEQ)   // 65536

typedef __attribute__((ext_vector_type(4))) float  floatx4;
typedef __attribute__((ext_vector_type(8))) short  short8;

// fp32 -> bf16 round-to-nearest-even
__device__ __forceinline__ unsigned short f2bf(float f) {
  unsigned int u = __float_as_uint(f);
  u += 0x7fffu + ((u >> 16) & 1u);
  return (unsigned short)(u >> 16);
}

// async global->LDS, 16B per lane; LDS dest = wave-uniform base + lane*16
__device__ __forceinline__ void async16(const void* g, void* l) {
  __builtin_amdgcn_global_load_lds(
      (const __attribute__((address_space(1))) unsigned int*)g,
      (__attribute__((address_space(3))) unsigned int*)l, 16, 0, 0);
}

__device__ __forceinline__ float fast_tanh(float x) {
  float e = __expf(2.0f * x);
  return 1.0f - 2.0f * __builtin_amdgcn_rcpf(1.0f + e);
}

// ---------------------------------------------------------------------------
// k_prep: three independent preprocessing jobs fused into one dispatch so
// they overlap on the device instead of serializing across launches.
//   blocks [0, 8192)      : Abf = bf16(enc_states), masked rows skipped
//   blocks [8192, 9216)   : Wt[n][k] = bf16(W_enc[k][n])
//   blocks [9216, 10240)  : dech[b][a] += dec[b]@W_dec (split-K x8) + biases
// ---------------------------------------------------------------------------
__global__ void k_prep(const float* __restrict__ enc, const int* __restrict__ enc_len,
                       unsigned short* __restrict__ Abf,
                       const float* __restrict__ W_enc, unsigned short* __restrict__ Wt,
                       const float* __restrict__ dec, const float* __restrict__ W_dec,
                       const float* __restrict__ b_dec, const float* __restrict__ b_enc,
                       float* __restrict__ dech) {
  int id = blockIdx.x;
  int tid = threadIdx.x;
  if (id < 8192) {
    // ---- convert enc_states -> bf16, 8 rows per block ----
    int b = id >> 8;
    int r0 = (id & 255) * 8;
    if (r0 >= enc_len[b]) return;
    size_t base = ((size_t)b * SEQ + r0) * DIM;
    const float4* src = (const float4*)(enc + base);
    ushort4* dst = (ushort4*)(Abf + base);
#pragma unroll
    for (int i = 0; i < 8; ++i) {
      float4 v = src[tid + i * 256];
      ushort4 h;
      h.x = f2bf(v.x); h.y = f2bf(v.y); h.z = f2bf(v.z); h.w = f2bf(v.w);
      dst[tid + i * 256] = h;
    }
  } else if (id < 9216) {
    // ---- transpose+convert W_enc ----
    int t = id - 8192;
    int n0 = (t & 31) * 32, k0 = (t >> 5) * 32;
    __shared__ float tile[32][33];
    int tx = tid & 31, ty = tid >> 5;     // 32 x 8
#pragma unroll
    for (int i = 0; i < 4; ++i) {
      int y = ty + i * 8;
      tile[y][tx] = W_enc[(size_t)(k0 + y) * DIM + n0 + tx];
    }
    __syncthreads();
#pragma unroll
    for (int i = 0; i < 4; ++i) {
      int y = ty + i * 8;
      Wt[(size_t)(n0 + y) * DIM + k0 + tx] = f2bf(tile[tx][y]);
    }
  } else {
    // ---- dec_h GEMV, split-K x8 ----
    int t = id - 9216;
    int x = t & 3, b = (t >> 2) & 31, z = t >> 7;
    int a = x * 256 + tid;
    float acc = (z == 0) ? (b_dec[a] + b_enc[a]) : 0.0f;
    const float* dr = dec + (size_t)b * DIM + z * 128;
    const float* wc = W_dec + (size_t)z * 128 * DIM + a;
#pragma unroll 8
    for (int e = 0; e < 128; ++e)
      acc = fmaf(dr[e], wc[(size_t)e * DIM], acc);
    atomicAdd(&dech[(size_t)b * DIM + a], acc);
  }
}

// ---------------------------------------------------------------------------
// GEMM + tanh-dot epilogue. 256x128 block tile, 128x64 wave tile (8x4 MFMA
// accs, 128 AGPRs), BK=32, 16x16x32 bf16 MFMA, 4 waves.
// LDS/iter: A 16 KB + B 8 KB staged via global_load_lds; fragment reads
// 4 waves x 12 KB. 34 B per kFLOP (was 47) -> LDS-BW cap lifted.
// ---------------------------------------------------------------------------
__global__ void __launch_bounds__(256, 2) k_gemm_bf16(
    const unsigned short* __restrict__ Abf, // [65536,1024] bf16
    const unsigned short* __restrict__ Wt,  // [1024 n][1024 k] bf16
    const float* __restrict__ dech,         // [32,1024]
    const float* __restrict__ w_attn,       // [1024]
    const int* __restrict__ enc_len,        // [32]
    float* __restrict__ score)              // [65536], pre-zeroed
{
  int linear = blockIdx.x;          // 0..2047
  int xcd = linear & 7;
  int j   = linear >> 3;            // 0..255
  int rb  = xcd * 32 + (j >> 3);    // row block (256 rows) 0..255
  int nb  = j & 7;                  // col block 0..7

  int bb  = rb >> 3;                // 8 row-blocks per batch
  int len = enc_len[bb];
  if (((rb & 7) * 256) >= len) return;   // fully masked tile

  __shared__ __align__(16) unsigned short sA[256 * 32];  // 16 KB, 64B rows
  __shared__ __align__(16) unsigned short sB[128 * 32];  // 8 KB

  int tid  = threadIdx.x;
  int w    = tid >> 6, lane = tid & 63;
  int wm   = (w >> 1) * 128, wn = (w & 1) * 64;
  int li   = lane & 15, g = lane >> 4;

  const unsigned short* Ab = Abf + (size_t)rb * 256 * DIM;
  const unsigned short* Bb = Wt  + (size_t)nb * 128 * DIM;

  floatx4 acc[8][4] = {};

  for (int kb = 0; kb < 32; ++kb) {
    __syncthreads();
    // stage A: 1024 16B-chunks (chunk p = row p>>2, quarter p&3), 16 segs
#pragma unroll
    for (int i = 0; i < 4; ++i) {
      int seg = i * 4 + w;                // wave-uniform
      int p   = seg * 64 + lane;
      int row = p >> 2, q = p & 3;
      async16(Ab + (size_t)row * DIM + kb * 32 + q * 8, (char*)sA + seg * 1024);
    }
    // stage B: 512 chunks, 8 segs
#pragma unroll
    for (int i = 0; i < 2; ++i) {
      int seg = i * 4 + w;
      int p   = seg * 64 + lane;
      int row = p >> 2, q = p & 3;
      async16(Bb + (size_t)row * DIM + kb * 32 + q * 8, (char*)sB + seg * 1024);
    }
    __syncthreads();

    short8 af[8], bfr[4];
#pragma unroll
    for (int t = 0; t < 8; ++t)
      af[t]  = *(const short8*)&sA[((wm + t * 16 + li) * 4 + g) * 8];
#pragma unroll
    for (int t = 0; t < 4; ++t)
      bfr[t] = *(const short8*)&sB[((wn + t * 16 + li) * 4 + g) * 8];
#pragma unroll
    for (int tm = 0; tm < 8; ++tm)
#pragma unroll
      for (int tn = 0; tn < 4; ++tn)
        acc[tm][tn] = __builtin_amdgcn_mfma_f32_16x16x32_bf16(af[tm], bfr[tn], acc[tm][tn], 0, 0, 0);
  }

  // epilogue: C/D layout col=lane&15, row=(lane>>4)*4+reg  [m89]
  float dh[4], wa[4];
#pragma unroll
  for (int tn = 0; tn < 4; ++tn) {
    int n = nb * 128 + wn + tn * 16 + li;
    dh[tn] = dech[(size_t)bb * DIM + n];
    wa[tn] = w_attn[n];
  }
#pragma unroll
  for (int tm = 0; tm < 8; ++tm) {
    int mrow = rb * 256 + wm + tm * 16 + g * 4;
#pragma unroll
    for (int r = 0; r < 4; ++r) {
      float v = 0.0f;
#pragma unroll
      for (int tn = 0; tn < 4; ++tn)
        v = fmaf(wa[tn], fast_tanh(acc[tm][tn][r] + dh[tn]), v);
      v += __shfl_xor(v, 1);
      v += __shfl_xor(v, 2);
      v += __shfl_xor(v, 4);
      v += __shfl_xor(v, 8);
      if (li == 0) atomicAdd(&score[mrow + r], v);
    }
  }
}

// ---------------------------------------------------------------------------
// masked softmax per batch row. SCALING == 1.0 (folded out).
// ---------------------------------------------------------------------------
__global__ void k_softmax(const float* __restrict__ score, const int* __restrict__ enc_len,
                          float* __restrict__ attn) {
  int b = blockIdx.x, tid = threadIdx.x;
  int len = enc_len[b];
  __shared__ float red[256];
  float v[8];
  float m = -1e30f;
#pragma unroll
  for (int i = 0; i < 8; ++i) {
    int s = tid + i * 256;
    v[i] = score[(size_t)b * SEQ + s];
    if (s < len) m = fmaxf(m, v[i]);
  }
  red[tid] = m; __syncthreads();
  for (int st = 128; st > 0; st >>= 1) {
    if (tid < st) red[tid] = fmaxf(red[tid], red[tid + st]);
    __syncthreads();
  }
  float mx = red[0]; __syncthreads();
  float sum = 0.0f;
#pragma unroll
  for (int i = 0; i < 8; ++i) {
    int s = tid + i * 256;
    float e = (s < len) ? __expf(v[i] - mx) : 0.0f;
    v[i] = e; sum += e;
  }
  red[tid] = sum; __syncthreads();
  for (int st = 128; st > 0; st >>= 1) {
    if (tid < st) red[tid] += red[tid + st];
    __syncthreads();
  }
  float inv = 1.0f / red[0];
#pragma unroll
  for (int i = 0; i < 8; ++i)
    attn[(size_t)b * SEQ + tid + i * 256] = v[i] * inv;
}

// ---------------------------------------------------------------------------
// ctx[b][e] += sum_s attn[b][s] * enc[b][s][e]   (memory-bound streaming)
// ---------------------------------------------------------------------------
__global__ void k_context(const float* __restrict__ enc, const float* __restrict__ attn,
                          const int* __restrict__ enc_len, float* __restrict__ ctx) {
  int b = blockIdx.y, sc = blockIdx.x;
  int len = enc_len[b];
  int s0 = sc * 64;
  if (s0 >= len) return;
  int cnt = min(64, len - s0);
  int tid = threadIdx.x;
  const float* base = enc + ((size_t)b * SEQ + s0) * DIM + tid * 4;
  const float* ap   = attn + (size_t)b * SEQ + s0;
  float a0 = 0.f, a1 = 0.f, a2 = 0.f, a3 = 0.f;
  for (int i = 0; i < cnt; ++i) {
    float a = ap[i];
    float4 x = *(const float4*)(base + (size_t)i * DIM);
    a0 = fmaf(a, x.x, a0); a1 = fmaf(a, x.y, a1);
    a2 = fmaf(a, x.z, a2); a3 = fmaf(a, x.w, a3);
  }
  float* c = ctx + (size_t)b * DIM + tid * 4;
  atomicAdd(c + 0, a0); atomicAdd(c + 1, a1);
  atomicAdd(c + 2, a2); atomicAdd(c + 3, a3);
}

// ---------------------------------------------------------------------------
// out[b][o] += ctx[b, z-chunk] @ W_out[z-chunk, o]  (split-K x8)
// ---------------------------------------------------------------------------
__global__ void k_out(const float* __restrict__ ctx, const float* __restrict__ W_out,
                      const float* __restrict__ b_out, float* __restrict__ out) {
  int b = blockIdx.y, z = blockIdx.z;
  int o = blockIdx.x * 256 + threadIdx.x;
  float acc = (z == 0) ? b_out[o] : 0.0f;
  const float* cr = ctx + (size_t)b * DIM + z * 128;
  const float* wc = W_out + (size_t)z * 128 * DIM + o;
#pragma unroll 8
  for (int e = 0; e < 128; ++e)
    acc = fmaf(cr[e], wc[(size_t)e * DIM], acc);
  atomicAdd(&out[(size_t)b * DIM + o], acc);
}

// ---------------------------------------------------------------------------
extern "C" void kernel_launch(void* const* d_in, const int* in_sizes, int n_in,
                              void* d_out, int out_size, void* d_ws, size_t ws_size,
                              hipStream_t stream) {
  (void)in_sizes; (void)n_in; (void)out_size; (void)ws_size;
  const float* enc_states = (const float*)d_in[0];   // [32,2048,1024]
  const float* dec_states = (const float*)d_in[1];   // [32,1024]
  const float* W_enc      = (const float*)d_in[2];   // [1024,1024]
  const float* b_enc      = (const float*)d_in[3];   // [1024]
  const float* W_dec      = (const float*)d_in[4];   // [1024,1024]
  const float* b_dec      = (const float*)d_in[5];   // [1024]
  const float* w_attn     = (const float*)d_in[6];   // [1024]
  const float* W_out      = (const float*)d_in[7];   // [1024,1024]
  const float* b_out      = (const float*)d_in[8];   // [1024]
  const int*   enc_len    = (const int*)  d_in[9];   // [32]

  float* out_ctx  = (float*)d_out;                   // [32,1024]
  float* out_attn = (float*)d_out + BATCH * DIM;     // [32,2048]

  // workspace layout:
  //   Wt    @ 0        : 2 MB   (bf16 W_enc^T)
  //   score @ 2 MB     : 256 KB (zeroed)
  //   ctx   @ 2.25 MB  : 128 KB (zeroed)
  //   dech  @ 2.375 MB : 128 KB (zeroed)
  //   Abf   @ 3 MB     : 128 MB (bf16 enc_states)
  char* ws = (char*)d_ws;
  unsigned short* Wt  = (unsigned short*)ws;
  float* score = (float*)(ws + (2u << 20));
  float* ctx   = (float*)(ws + (2u << 20) + 262144);
  float* dech  = (float*)(ws + (2u << 20) + 262144 + 131072);
  unsigned short* Abf = (unsigned short*)(ws + (3u << 20));

  // zero score + ctx + dech (all atomically accumulated)
  hipMemsetAsync(ws + (2u << 20), 0, 262144 + 131072 + 131072, stream);
  // zero out_ctx (atomically accumulated by k_out)
  hipMemsetAsync(d_out, 0, (size_t)BATCH * DIM * sizeof(float), stream);

  k_prep<<<10240, 256, 0, stream>>>(enc_states, enc_len, Abf, W_enc, Wt,
                                    dec_states, W_dec, b_dec, b_enc, dech);
  k_gemm_bf16<<<2048, 256, 0, stream>>>(Abf, Wt, dech, w_attn, enc_len, score);
  k_softmax<<<BATCH, 256, 0, stream>>>(score, enc_len, out_attn);
  k_context<<<dim3(32, BATCH), 256, 0, stream>>>(enc_states, out_attn, enc_len, ctx);
  k_out<<<dim3(4, BATCH, 8), 256, 0, stream>>>(ctx, W_out, b_out, out_ctx);
}